// Round 1
// baseline (351.871 us; speedup 1.0000x reference)
//
#include <hip/hip_runtime.h>
#include <hip/hip_bf16.h>

#define B_ 4
#define S_ 2048
#define H_ 8
#define DH_ 64
#define HID_ 512
#define LOG2E 1.4426950408889634f

typedef __attribute__((ext_vector_type(4))) float f32x4;
typedef __attribute__((ext_vector_type(8))) short short8;

__device__ __forceinline__ unsigned short f2bf(float f) {
    __hip_bfloat16 h = __float2bfloat16(f);
    return __builtin_bit_cast(unsigned short, h);
}

// ---------------- QKV projection (fp32 math, bf16 output) ----------------
// grid: (B*S/256, H, 4)  block: 256.  Each thread: one token, one head,
// 16 output dims (e) for q,k,v.  W reads are wave-uniform -> scalar loads.
__global__ __launch_bounds__(256) void qkv_proj_kernel(
    const float* __restrict__ x,
    const float* __restrict__ Wq, const float* __restrict__ bq,
    const float* __restrict__ Wk, const float* __restrict__ bk,
    const float* __restrict__ Wv, const float* __restrict__ bv,
    unsigned short* __restrict__ Qb, unsigned short* __restrict__ Kb,
    unsigned short* __restrict__ Vb)
{
    const int h  = blockIdx.y;
    const int e0 = blockIdx.z * 16;
    const int token = blockIdx.x * 256 + threadIdx.x;   // 0..B*S-1
    const int b = token >> 11;
    const int s = token & (S_ - 1);

    const float* xp = x + (size_t)token * HID_ + h * DH_;
    float xr[DH_];
#pragma unroll
    for (int i = 0; i < DH_ / 4; ++i) {
        const float4 v = *reinterpret_cast<const float4*>(xp + 4 * i);
        xr[4*i+0] = v.x; xr[4*i+1] = v.y; xr[4*i+2] = v.z; xr[4*i+3] = v.w;
    }

    const float* wq = Wq + h * DH_ * DH_;
    const float* wk = Wk + h * DH_ * DH_;
    const float* wv = Wv + h * DH_ * DH_;
    const float* bqh = bq + h * DH_;
    const float* bkh = bk + h * DH_;
    const float* bvh = bv + h * DH_;

    const size_t ob = (((size_t)b * H_ + h) * S_ + s) * DH_;

#pragma unroll
    for (int c8 = 0; c8 < 2; ++c8) {
        short8 uq, uk, uv;
#pragma unroll
        for (int ee = 0; ee < 8; ++ee) {
            const int e = e0 + c8 * 8 + ee;
            float aq = bqh[e], ak = bkh[e], av = bvh[e];
            const float* wqe = wq + e * DH_;
            const float* wke = wk + e * DH_;
            const float* wve = wv + e * DH_;
#pragma unroll
            for (int d = 0; d < DH_; ++d) {
                aq = fmaf(xr[d], wqe[d], aq);
                ak = fmaf(xr[d], wke[d], ak);
                av = fmaf(xr[d], wve[d], av);
            }
            uq[ee] = (short)f2bf(aq * 0.125f);   // fold 1/sqrt(DH) into Q
            uk[ee] = (short)f2bf(ak);
            uv[ee] = (short)f2bf(av);
        }
        *reinterpret_cast<short8*>(Qb + ob + e0 + c8 * 8) = uq;
        *reinterpret_cast<short8*>(Kb + ob + e0 + c8 * 8) = uk;
        *reinterpret_cast<short8*>(Vb + ob + e0 + c8 * 8) = uv;
    }
}

// ---------------- fused flash attention, bf16 MFMA ----------------
// grid: (S/128, B*H)  block: 256 (4 waves).  Wave owns 32 q-rows (2 M-tiles).
// KV tiles of 32 staged in LDS (K row-major padded; V transposed at staging).
__global__ __launch_bounds__(256) void attn_kernel(
    const unsigned short* __restrict__ Qb,
    const unsigned short* __restrict__ Kb,
    const unsigned short* __restrict__ Vb,
    float* __restrict__ out)
{
    __shared__ unsigned short Kl[32][72];     // 32 kv x 64 d, +8 pad (2-way banks)
    __shared__ unsigned short Vt[DH_][40];    // 64 d x 32 kv, +8 pad
    __shared__ unsigned short Pl[4][32][40];  // per-wave P redistribution

    const int bh = blockIdx.y;          // b*H + h
    const int b  = bh >> 3;
    const int h  = bh & 7;
    const int tid  = threadIdx.x;
    const int w    = tid >> 6;
    const int lane = tid & 63;
    const int g = lane >> 4;            // 0..3
    const int c = lane & 15;            // 0..15

    const size_t base = (size_t)bh * S_ * DH_;
    const int q0 = blockIdx.x * 128 + w * 32;

    // Q A-fragments: row = lane&15, k = (lane>>4)*8 + j   (k-slice ks: +32*ks)
    short8 aq[2][2];
#pragma unroll
    for (int mt = 0; mt < 2; ++mt)
#pragma unroll
      for (int ks = 0; ks < 2; ++ks)
        aq[mt][ks] = *reinterpret_cast<const short8*>(
            Qb + base + (size_t)(q0 + mt*16 + c) * DH_ + ks*32 + g*8);

    f32x4 o[2][4];
    float m_[2][4], l_[2][4];
#pragma unroll
    for (int mt = 0; mt < 2; ++mt)
#pragma unroll
      for (int r = 0; r < 4; ++r) { m_[mt][r] = -INFINITY; l_[mt][r] = 0.f; }
#pragma unroll
    for (int mt = 0; mt < 2; ++mt)
#pragma unroll
      for (int n = 0; n < 4; ++n) o[mt][n] = (f32x4){0.f, 0.f, 0.f, 0.f};

    const int krow = tid >> 3;        // 0..31
    const int kc8  = (tid & 7) * 8;   // 0..56

    for (int t = 0; t < S_ / 32; ++t) {
        const int kv0 = t * 32;
        __syncthreads();
        // stage K tile (coalesced 16B per thread)
        const short8 kvK = *reinterpret_cast<const short8*>(
            Kb + base + (size_t)(kv0 + krow) * DH_ + kc8);
        *reinterpret_cast<short8*>(&Kl[krow][kc8]) = kvK;
        // stage V transposed (coalesced read, scalar LDS writes)
        const short8 kvV = *reinterpret_cast<const short8*>(
            Vb + base + (size_t)(kv0 + krow) * DH_ + kc8);
#pragma unroll
        for (int i = 0; i < 8; ++i)
            Vt[kc8 + i][krow] = (unsigned short)kvV[i];
        __syncthreads();

        // QK^T: B[k=d][n=kv] = K[kv][d] -> b128 reads from Kl
        short8 bk_[2][2];
#pragma unroll
        for (int n = 0; n < 2; ++n)
#pragma unroll
          for (int ks = 0; ks < 2; ++ks)
            bk_[n][ks] = *reinterpret_cast<const short8*>(&Kl[n*16 + c][ks*32 + g*8]);

        f32x4 s[2][2];
#pragma unroll
        for (int mt = 0; mt < 2; ++mt)
#pragma unroll
          for (int n = 0; n < 2; ++n) {
            f32x4 acc = (f32x4){0.f, 0.f, 0.f, 0.f};
            acc = __builtin_amdgcn_mfma_f32_16x16x32_bf16(aq[mt][0], bk_[n][0], acc, 0, 0, 0);
            acc = __builtin_amdgcn_mfma_f32_16x16x32_bf16(aq[mt][1], bk_[n][1], acc, 0, 0, 0);
            s[mt][n] = acc;
          }

        // online softmax (C-frag: row = g*4+r, col = c; reduce over 16 lanes)
#pragma unroll
        for (int mt = 0; mt < 2; ++mt) {
            float pm[4], sc[4], rs[4];
#pragma unroll
            for (int r = 0; r < 4; ++r) pm[r] = fmaxf(s[mt][0][r], s[mt][1][r]);
#pragma unroll
            for (int off = 1; off <= 8; off <<= 1)
#pragma unroll
              for (int r = 0; r < 4; ++r)
                pm[r] = fmaxf(pm[r], __shfl_xor(pm[r], off));
#pragma unroll
            for (int r = 0; r < 4; ++r) {
                const float mn = fmaxf(m_[mt][r], pm[r]);
                sc[r] = __builtin_amdgcn_exp2f((m_[mt][r] - mn) * LOG2E);
                m_[mt][r] = mn;
                rs[r] = 0.f;
            }
#pragma unroll
            for (int n = 0; n < 2; ++n)
#pragma unroll
              for (int r = 0; r < 4; ++r) {
                const float p = __builtin_amdgcn_exp2f((s[mt][n][r] - m_[mt][r]) * LOG2E);
                rs[r] += p;
                Pl[w][mt*16 + g*4 + r][n*16 + c] = f2bf(p);
              }
#pragma unroll
            for (int off = 1; off <= 8; off <<= 1)
#pragma unroll
              for (int r = 0; r < 4; ++r)
                rs[r] += __shfl_xor(rs[r], off);
#pragma unroll
            for (int r = 0; r < 4; ++r) l_[mt][r] = l_[mt][r] * sc[r] + rs[r];
#pragma unroll
            for (int n = 0; n < 4; ++n) {
                f32x4 t4 = o[mt][n];
#pragma unroll
                for (int r = 0; r < 4; ++r) t4[r] *= sc[r];
                o[mt][n] = t4;
            }
        }

        // PV: A = P (b128 from Pl), B[k=kv][n=d] = Vt[d][kv] (b128 from Vt)
        short8 bv_[4];
#pragma unroll
        for (int n = 0; n < 4; ++n)
            bv_[n] = *reinterpret_cast<const short8*>(&Vt[n*16 + c][g*8]);
        short8 pa[2];
#pragma unroll
        for (int mt = 0; mt < 2; ++mt)
            pa[mt] = *reinterpret_cast<const short8*>(&Pl[w][mt*16 + c][g*8]);
#pragma unroll
        for (int mt = 0; mt < 2; ++mt)
#pragma unroll
          for (int n = 0; n < 4; ++n)
            o[mt][n] = __builtin_amdgcn_mfma_f32_16x16x32_bf16(pa[mt], bv_[n], o[mt][n], 0, 0, 0);
    }

    // epilogue: divide by l, scatter to [B,S,HID] fp32
#pragma unroll
    for (int mt = 0; mt < 2; ++mt)
#pragma unroll
      for (int n = 0; n < 4; ++n)
#pragma unroll
        for (int r = 0; r < 4; ++r) {
            const int q = q0 + mt*16 + g*4 + r;
            const int d = n*16 + c;
            out[((size_t)(b * S_ + q)) * HID_ + h * DH_ + d] = o[mt][n][r] / l_[mt][r];
        }
}

extern "C" void kernel_launch(void* const* d_in, const int* in_sizes, int n_in,
                              void* d_out, int out_size, void* d_ws, size_t ws_size,
                              hipStream_t stream)
{
    const float* x  = (const float*)d_in[0];
    const float* Wq = (const float*)d_in[1];
    const float* bq = (const float*)d_in[2];
    const float* Wk = (const float*)d_in[3];
    const float* bk = (const float*)d_in[4];
    const float* Wv = (const float*)d_in[5];
    const float* bv = (const float*)d_in[6];
    float* out = (float*)d_out;

    unsigned short* Qb = (unsigned short*)d_ws;                 // [B,H,S,DH] bf16
    unsigned short* Kb = Qb + (size_t)B_ * H_ * S_ * DH_;
    unsigned short* Vb = Kb + (size_t)B_ * H_ * S_ * DH_;

    dim3 gp(B_ * S_ / 256, H_, 4);
    qkv_proj_kernel<<<gp, 256, 0, stream>>>(x, Wq, bq, Wk, bk, Wv, bv, Qb, Kb, Vb);

    dim3 ga(S_ / 128, B_ * H_, 1);
    attn_kernel<<<ga, 256, 0, stream>>>(Qb, Kb, Vb, out);
}